// Round 5
// baseline (1748.850 us; speedup 1.0000x reference)
//
#include <hip/hip_runtime.h>

#define HW 4096

__device__ __forceinline__ float hswish(float x) {
  float r = fminf(fmaxf(x + 3.0f, 0.0f), 6.0f);
  return x * r * (1.0f / 6.0f);
}

__device__ __forceinline__ void atomic_add_f32(float* p, float v) {
  __hip_atomic_fetch_add(p, v, __ATOMIC_RELAXED, __HIP_MEMORY_SCOPE_AGENT);
}

// zero n4 float4s
__global__ __launch_bounds__(256) void zero_buf4(float4* __restrict__ p, int n4) {
  int i = blockIdx.x * 256 + threadIdx.x;
  if (i < n4) p[i] = make_float4(0.f, 0.f, 0.f, 0.f);
}

// In-place epilogue over a (B,C,HW) buffer, float4-vectorized.
// mode 1: g*x+b   mode 2: hswish(g*x+b)
__global__ __launch_bounds__(256) void epi_pass(
    float* __restrict__ buf, const float* __restrict__ scale,
    const float* __restrict__ bias, int Cmask, int mode)
{
  int i = blockIdx.x * 256 + threadIdx.x;      // float4 index
  int c = (i >> 10) & Cmask;                   // HW/4 = 1024 float4 per channel
  float4 v = ((float4*)buf)[i];
  float g = scale[c], bb = bias[c];
  float* f = &v.x;
  #pragma unroll
  for (int j = 0; j < 4; ++j) {
    float x = f[j] * g + bb;
    f[j] = (mode == 2) ? hswish(x) : x;
  }
  ((float4*)buf)[i] = v;
}

// 1x1 conv GEMM, 128x128 tile, fused epilogue (for CO=1024 GEMMs with >=4 blocks/CU).
// Grid dim3(32, CO/128, B). epi: 0 none, 3 hswish(x+bias)
__global__ __launch_bounds__(256) void gemm1x1_big(
    const float* __restrict__ in0, const float* __restrict__ in1,
    const float* __restrict__ W, float* __restrict__ out,
    const float* __restrict__ scale, const float* __restrict__ bias,
    int K, int k0, int CO, int epi)
{
  __shared__ float At[8][128];
  __shared__ float Wt[8][128];
  const int p0  = blockIdx.x * 128;
  const int co0 = blockIdx.y * 128;
  const int b   = blockIdx.z;
  const int tid = threadIdx.x;
  const int tx = tid & 15, ty = tid >> 4;
  const int k1 = K - k0;
  const int ar = tid >> 5, ac = (tid & 31) << 2;
  const int wco = tid >> 1, wk = (tid & 1) << 2;
  float acc[8][8] = {};
  for (int kt = 0; kt < K; kt += 8) {
    {
      int kg = kt + ar;
      const float* src = (kg < k0)
          ? in0 + ((size_t)b * k0 + kg) * HW
          : in1 + ((size_t)b * k1 + (kg - k0)) * HW;
      *(float4*)&At[ar][ac] = *(const float4*)(src + p0 + ac);
    }
    {
      float4 wv = *(const float4*)(W + (size_t)(co0 + wco) * K + kt + wk);
      Wt[wk + 0][wco] = wv.x; Wt[wk + 1][wco] = wv.y;
      Wt[wk + 2][wco] = wv.z; Wt[wk + 3][wco] = wv.w;
    }
    __syncthreads();
    #pragma unroll
    for (int k = 0; k < 8; ++k) {
      float4 a0 = *(const float4*)&At[k][tx << 2];
      float4 a1 = *(const float4*)&At[k][(tx << 2) + 64];
      float4 w0 = *(const float4*)&Wt[k][ty << 2];
      float4 w1 = *(const float4*)&Wt[k][(ty << 2) + 64];
      float av[8] = {a0.x, a0.y, a0.z, a0.w, a1.x, a1.y, a1.z, a1.w};
      float wv[8] = {w0.x, w0.y, w0.z, w0.w, w1.x, w1.y, w1.z, w1.w};
      #pragma unroll
      for (int i = 0; i < 8; ++i)
        #pragma unroll
        for (int j = 0; j < 8; ++j)
          acc[i][j] = fmaf(wv[i], av[j], acc[i][j]);
    }
    __syncthreads();
  }
  #pragma unroll
  for (int i = 0; i < 8; ++i) {
    int co = co0 + (ty << 2) + (i & 3) + (i >> 2) * 64;
    float bb = (epi == 3) ? bias[co] : 0.0f;
    float vv[8];
    #pragma unroll
    for (int j = 0; j < 8; ++j) {
      float v = acc[i][j];
      if (epi == 3) v = hswish(v + bb);
      vv[j] = v;
    }
    float* op = out + ((size_t)b * CO + co) * HW + p0;
    *(float4*)(op + (tx << 2))      = make_float4(vv[0], vv[1], vv[2], vv[3]);
    *(float4*)(op + (tx << 2) + 64) = make_float4(vv[4], vv[5], vv[6], vv[7]);
  }
}

// Split-K variant: block handles K range [s*kc, (s+1)*kc), atomically accumulates
// into a pre-zeroed output. Grid dim3(32, CO/128, B << slog); nsplit = 1<<slog.
__global__ __launch_bounds__(256) void gemm1x1_split(
    const float* __restrict__ in0, const float* __restrict__ in1,
    const float* __restrict__ W, float* __restrict__ out,
    int K, int k0, int CO, int kc, int slog)
{
  __shared__ float At[8][128];
  __shared__ float Wt[8][128];
  const int p0  = blockIdx.x * 128;
  const int co0 = blockIdx.y * 128;
  const int s   = blockIdx.z & ((1 << slog) - 1);
  const int b   = blockIdx.z >> slog;
  const int tid = threadIdx.x;
  const int tx = tid & 15, ty = tid >> 4;
  const int k1 = K - k0;
  const int ar = tid >> 5, ac = (tid & 31) << 2;
  const int wco = tid >> 1, wk = (tid & 1) << 2;
  const int kbeg = s * kc, kend = kbeg + kc;
  float acc[8][8] = {};
  for (int kt = kbeg; kt < kend; kt += 8) {
    {
      int kg = kt + ar;
      const float* src = (kg < k0)
          ? in0 + ((size_t)b * k0 + kg) * HW
          : in1 + ((size_t)b * k1 + (kg - k0)) * HW;
      *(float4*)&At[ar][ac] = *(const float4*)(src + p0 + ac);
    }
    {
      float4 wv = *(const float4*)(W + (size_t)(co0 + wco) * K + kt + wk);
      Wt[wk + 0][wco] = wv.x; Wt[wk + 1][wco] = wv.y;
      Wt[wk + 2][wco] = wv.z; Wt[wk + 3][wco] = wv.w;
    }
    __syncthreads();
    #pragma unroll
    for (int k = 0; k < 8; ++k) {
      float4 a0 = *(const float4*)&At[k][tx << 2];
      float4 a1 = *(const float4*)&At[k][(tx << 2) + 64];
      float4 w0 = *(const float4*)&Wt[k][ty << 2];
      float4 w1 = *(const float4*)&Wt[k][(ty << 2) + 64];
      float av[8] = {a0.x, a0.y, a0.z, a0.w, a1.x, a1.y, a1.z, a1.w};
      float wv[8] = {w0.x, w0.y, w0.z, w0.w, w1.x, w1.y, w1.z, w1.w};
      #pragma unroll
      for (int i = 0; i < 8; ++i)
        #pragma unroll
        for (int j = 0; j < 8; ++j)
          acc[i][j] = fmaf(wv[i], av[j], acc[i][j]);
    }
    __syncthreads();
  }
  #pragma unroll
  for (int i = 0; i < 8; ++i) {
    int co = co0 + (ty << 2) + (i & 3) + (i >> 2) * 64;
    float* op = out + ((size_t)b * CO + co) * HW + p0;
    #pragma unroll
    for (int j = 0; j < 8; ++j) {
      int col = (tx << 2) + (j & 3) + (j >> 2) * 64;
      atomic_add_f32(op + col, acc[i][j]);
    }
  }
}

// LDS-tiled depthwise 3x3, pad 1, branch-free inner loop. One block per (b,c).
// epi: 2 hswish(scale*x+bias), 3 hswish(x+bias)
__global__ __launch_bounds__(256) void dwconv3(
    const float* __restrict__ in, const float* __restrict__ w,
    float* __restrict__ out, const float* __restrict__ scale,
    const float* __restrict__ bias, int Cmask, int epi)
{
  __shared__ float tl[66 * 66];
  const int bc = blockIdx.x;
  const int c  = bc & Cmask;
  const float* src = in + (size_t)bc * HW;
  const int t = threadIdx.x;
  for (int i = t; i < 66 * 66; i += 256) {
    int r = i / 66, cc = i - r * 66;
    int gy = r - 1, gx = cc - 1;
    float v = 0.0f;
    if (gy >= 0 && gy < 64 && gx >= 0 && gx < 64) v = src[(gy << 6) + gx];
    tl[i] = v;
  }
  const float* wp = w + c * 9;
  float w00 = wp[0], w01 = wp[1], w02 = wp[2];
  float w10 = wp[3], w11 = wp[4], w12 = wp[5];
  float w20 = wp[6], w21 = wp[7], w22 = wp[8];
  float g = (epi == 2) ? scale[c] : 1.0f;
  float bb = bias[c];
  __syncthreads();
  float* op = out + (size_t)bc * HW;
  #pragma unroll 4
  for (int j = 0; j < 16; ++j) {
    int p = j * 256 + t;
    int y = p >> 6, x = p & 63;
    const float* bp = &tl[y * 66 + x];
    float s;
    s = w00 * bp[0]        + w01 * bp[1]        + w02 * bp[2];
    s = fmaf(w10, bp[66],    fmaf(w11, bp[67],    fmaf(w12, bp[68],  s)));
    s = fmaf(w20, bp[132],   fmaf(w21, bp[133],   fmaf(w22, bp[134], s)));
    float v = (epi == 2) ? hswish(s * g + bb) : hswish(s + bb);
    op[p] = v;
  }
}

// Fused dw5x5(pad2) + grouped 1x1 (32->32 per group).
__global__ __launch_bounds__(256) void agg_fused(
    const float* __restrict__ in, const float* __restrict__ dw,
    const float* __restrict__ pw, float* __restrict__ out, int C)
{
  __shared__ float in_t[16 * 12 * 68];
  __shared__ float dww[32 * 25];
  __shared__ float pww[32 * 32];
  const int g = blockIdx.x, b = blockIdx.y, tile = blockIdx.z;
  const int t = threadIdx.x;
  const int y0 = tile * 8;
  const float* src = in + ((size_t)b * C + g * 32) * HW;

  for (int i = t; i < 800; i += 256)  dww[i] = dw[(size_t)g * 800 + i];
  for (int i = t; i < 1024; i += 256) pww[i] = pw[(size_t)g * 1024 + i];

  const int x = t & 63, yl = t >> 6;
  float acca[32] = {}, accb[32] = {};

  for (int ph = 0; ph < 2; ++ph) {
    __syncthreads();
    #pragma unroll
    for (int i = 0; i < 12; ++i) {
      int id = i * 256 + t;
      int q = id & 15;
      int rid = id >> 4;
      int ch = rid / 12, r = rid - ch * 12;
      int gy = y0 - 2 + r;
      float4 v = make_float4(0.f, 0.f, 0.f, 0.f);
      if (gy >= 0 && gy < 64)
        v = *(const float4*)(src + (size_t)(ph * 16 + ch) * HW + (gy << 6) + (q << 2));
      *(float4*)&in_t[(ch * 12 + r) * 68 + 2 + (q << 2)] = v;
    }
    #pragma unroll
    for (int i = 0; i < 3; ++i) {
      int id = i * 256 + t;
      int side = id & 3;
      int rid = id >> 2;
      int col = (side < 2) ? side : 64 + side;
      in_t[rid * 68 + col] = 0.0f;
    }
    __syncthreads();
    for (int cl = 0; cl < 16; ++cl) {
      int ci = ph * 16 + cl;
      const float* bp = &in_t[(cl * 12) * 68 + 2 + x];
      const float* wv = &dww[ci * 25];
      float da = 0.f, db = 0.f;
      #pragma unroll
      for (int k = 0; k < 25; ++k) {
        int dy = k / 5, dx = (k % 5) - 2;
        float w = wv[k];
        da = fmaf(w, bp[(yl + dy) * 68 + dx], da);
        db = fmaf(w, bp[(yl + 4 + dy) * 68 + dx], db);
      }
      #pragma unroll
      for (int m = 0; m < 32; ++m) {
        float w = pww[m * 32 + ci];
        acca[m] = fmaf(w, da, acca[m]);
        accb[m] = fmaf(w, db, accb[m]);
      }
    }
  }
  float* dst = out + ((size_t)b * C + g * 32) * HW + y0 * 64;
  #pragma unroll
  for (int m = 0; m < 32; ++m) {
    dst[(size_t)m * HW + (yl << 6) + x]        = acca[m];
    dst[(size_t)m * HW + ((yl + 4) << 6) + x]  = accb[m];
  }
}

// Attention phase A: partial ctx = K^T [V|1] over a 128-n slice, atomicAdd to ctxbuf.
__global__ __launch_bounds__(256) void att_ctx(
    const float* __restrict__ kv, const float* __restrict__ kvs,
    float* __restrict__ ctxbuf)
{
  __shared__ float kvt[64][129];
  const int head  = blockIdx.x;
  const int b     = blockIdx.y;
  const int slice = blockIdx.z & 31;
  const int z     = blockIdx.z >> 5;
  const int tid   = threadIdx.x;

  const float* kvsrc = (head < 8)
      ? kv  + ((size_t)b * 1024 + z * 512 + head * 64) * HW
      : kvs + ((size_t)b * 1024 + z * 512 + (head - 8) * 64) * HW;
  const int n0 = slice * 128;

  #pragma unroll
  for (int l = 0; l < 8; ++l) {
    int fid = tid + l * 256;
    int ch = fid >> 5;
    int nc = (fid & 31) << 2;
    float4 v = *(const float4*)(kvsrc + (size_t)ch * HW + n0 + nc);
    if (ch < 32) {
      v.x = fmaxf(v.x, 0.0f); v.y = fmaxf(v.y, 0.0f);
      v.z = fmaxf(v.z, 0.0f); v.w = fmaxf(v.w, 0.0f);
    }
    kvt[ch][nc] = v.x; kvt[ch][nc + 1] = v.y;
    kvt[ch][nc + 2] = v.z; kvt[ch][nc + 3] = v.w;
  }
  __syncthreads();

  const int td = tid & 15, te = tid >> 4;
  const int d0 = td * 2, e0 = te * 2;
  float a00 = 0, a01 = 0, a10 = 0, a11 = 0, c0 = 0, c1 = 0;
  #pragma unroll 8
  for (int nn = 0; nn < 128; ++nn) {
    float k0 = kvt[d0][nn], k1 = kvt[d0 + 1][nn];
    float v0 = kvt[32 + e0][nn], v1 = kvt[32 + e0 + 1][nn];
    a00 = fmaf(k0, v0, a00); a01 = fmaf(k0, v1, a01);
    a10 = fmaf(k1, v0, a10); a11 = fmaf(k1, v1, a11);
    c0 += k0; c1 += k1;
  }
  float* cp = ctxbuf + (size_t)(((z * 4 + b) * 16) + head) * 1056;
  atomic_add_f32(&cp[(d0 + 0) * 33 + e0 + 0], a00);
  atomic_add_f32(&cp[(d0 + 0) * 33 + e0 + 1], a01);
  atomic_add_f32(&cp[(d0 + 1) * 33 + e0 + 0], a10);
  atomic_add_f32(&cp[(d0 + 1) * 33 + e0 + 1], a11);
  if (te == 0) {
    atomic_add_f32(&cp[(d0 + 0) * 33 + 32], c0);
    atomic_add_f32(&cp[(d0 + 1) * 33 + 32], c1);
  }
}

// Attention phase B.
__global__ __launch_bounds__(256) void att_apply(
    const float* __restrict__ ctxbuf,
    const float* __restrict__ q0, const float* __restrict__ q0s,
    const float* __restrict__ q1, const float* __restrict__ q1s,
    float* __restrict__ outbase, size_t outstride)
{
  __shared__ float ctx[1056];
  const int head = blockIdx.x;
  const int b    = blockIdx.y;
  const int tile = blockIdx.z & 15;
  const int z    = blockIdx.z >> 4;
  const int tid  = threadIdx.x;

  const float* cp = ctxbuf + (size_t)(((z * 4 + b) * 16) + head) * 1056;
  for (int i = tid; i < 1056; i += 256) ctx[i] = cp[i];
  __syncthreads();

  const float* qb = (z == 0) ? (head < 8 ? q0 : q0s) : (head < 8 ? q1 : q1s);
  const float* qsrc = qb + ((size_t)b * 256 + (head & 7) * 32) * HW;
  float* outp = outbase + (size_t)z * outstride + ((size_t)b * 512 + head * 32) * HW;

  const int n = tile * 256 + tid;
  float qv[32];
  #pragma unroll
  for (int d = 0; d < 32; ++d)
    qv[d] = fmaxf(qsrc[(size_t)d * HW + n], 0.0f);
  float den = 1e-15f;
  #pragma unroll
  for (int d = 0; d < 32; ++d)
    den = fmaf(qv[d], ctx[d * 33 + 32], den);
  float rden = 1.0f / den;
  for (int e = 0; e < 32; ++e) {
    float s = 0.0f;
    #pragma unroll
    for (int d = 0; d < 32; ++d)
      s = fmaf(qv[d], ctx[d * 33 + e], s);
    outp[(size_t)e * HW + n] = s * rden;
  }
}

extern "C" void kernel_launch(void* const* d_in, const int* in_sizes, int n_in,
                              void* d_out, int out_size, void* d_ws, size_t ws_size,
                              hipStream_t stream) {
  (void)in_sizes; (void)n_in; (void)out_size; (void)ws_size;
  const float* rgb         = (const float*)d_in[0];
  const float* t           = (const float*)d_in[1];
  const float* m1_inv_w    = (const float*)d_in[2];
  const float* m1_inv_g    = (const float*)d_in[3];
  const float* m1_inv_b    = (const float*)d_in[4];
  const float* m1_dw_w     = (const float*)d_in[5];
  const float* m1_dw_g     = (const float*)d_in[6];
  const float* m1_dw_b     = (const float*)d_in[7];
  const float* m1_pw_w     = (const float*)d_in[8];
  const float* m1_pw_g     = (const float*)d_in[9];
  const float* m1_pw_b     = (const float*)d_in[10];
  const float* kv_w        = (const float*)d_in[11];
  const float* qrgb_w      = (const float*)d_in[12];
  const float* qt_w        = (const float*)d_in[13];
  const float* agg_kv_dw   = (const float*)d_in[14];
  const float* agg_kv_pw   = (const float*)d_in[15];
  const float* agg_t_dw    = (const float*)d_in[16];
  const float* agg_t_pw    = (const float*)d_in[17];
  const float* agg_rgb_dw  = (const float*)d_in[18];
  const float* agg_rgb_pw  = (const float*)d_in[19];
  const float* proj_w      = (const float*)d_in[20];
  const float* m2_inv_w    = (const float*)d_in[21];
  const float* m2_inv_bias = (const float*)d_in[22];
  const float* m2_dw_w     = (const float*)d_in[23];
  const float* m2_dw_bias  = (const float*)d_in[24];
  const float* m2_pw_w     = (const float*)d_in[25];
  const float* m2_pw_g     = (const float*)d_in[26];
  const float* m2_pw_b     = (const float*)d_in[27];
  float* outp = (float*)d_out;

  const size_t S = (size_t)4 * 256 * HW;   // one (B,256,64,64) fp32 tensor
  const int S4 = (int)(S / 4);
  float* ws   = (float*)d_ws;
  float* bufA = ws;            // S
  float* bufB = ws + S;        // S
  float* bufE = ws + 2 * S;    // S (qt_s)
  float* bufF = ws + 3 * S;    // S (qrgb_s)
  float* KV   = ws + 4 * S;    // 4S (kv; later out1|out2)
  float* C4   = ws + 8 * S;    // 4S (ctxbuf; later m2_inv out)
  float* D4   = ws + 12 * S;   // 4S (kv_s; later m2_dw out)

  dim3 blk(256);
  const int ZG = S4 / 256;     // 4096 blocks for one S-tensor

  // m1 stem: inv (split-K 2) + epi, dw3x3, pw (split-K 2) + epi
  zero_buf4<<<dim3(ZG), blk, 0, stream>>>((float4*)bufA, S4);
  gemm1x1_split<<<dim3(32, 2, 8), blk, 0, stream>>>(rgb, t, m1_inv_w, bufA, 512, 256, 256, 256, 1);
  epi_pass<<<dim3(ZG), blk, 0, stream>>>(bufA, m1_inv_g, m1_inv_b, 255, 2);
  dwconv3<<<dim3(1024), blk, 0, stream>>>(bufA, m1_dw_w, bufB, m1_dw_g, m1_dw_b, 255, 2);
  zero_buf4<<<dim3(ZG), blk, 0, stream>>>((float4*)bufA, S4);
  gemm1x1_split<<<dim3(32, 2, 8), blk, 0, stream>>>(bufB, bufB, m1_pw_w, bufA, 256, 256, 256, 128, 1);
  epi_pass<<<dim3(ZG), blk, 0, stream>>>(bufA, m1_pw_g, m1_pw_b, 255, 1);   // rgbt -> A

  // projections: kv fused (1024 blocks); qt/qrgb split-K 2
  gemm1x1_big<<<dim3(32, 8, 4), blk, 0, stream>>>(bufA, bufA, kv_w, KV, nullptr, nullptr, 256, 256, 1024, 0);
  zero_buf4<<<dim3(ZG), blk, 0, stream>>>((float4*)bufB, S4);
  gemm1x1_split<<<dim3(32, 2, 8), blk, 0, stream>>>(t, t, qt_w, bufB, 256, 256, 256, 128, 1);       // q_t -> B
  zero_buf4<<<dim3(ZG), blk, 0, stream>>>((float4*)bufA, S4);
  gemm1x1_split<<<dim3(32, 2, 8), blk, 0, stream>>>(rgb, rgb, qrgb_w, bufA, 256, 256, 256, 128, 1); // q_rgb -> A

  // fused multi-scale aggregation (dw5x5 + grouped 1x1)
  agg_fused<<<dim3(32, 4, 8), blk, 0, stream>>>(KV,  agg_kv_dw,  agg_kv_pw,  D4,  1024);  // kv_s -> D4
  agg_fused<<<dim3(8, 4, 8),  blk, 0, stream>>>(bufB, agg_t_dw,  agg_t_pw,  bufE, 256);   // qt_s -> E
  agg_fused<<<dim3(8, 4, 8),  blk, 0, stream>>>(bufA, agg_rgb_dw, agg_rgb_pw, bufF, 256); // qrgb_s -> F

  // attention
  zero_buf4<<<dim3(132), blk, 0, stream>>>((float4*)C4, 128 * 264);
  att_ctx<<<dim3(16, 4, 64), blk, 0, stream>>>(KV, D4, C4);
  att_apply<<<dim3(16, 4, 32), blk, 0, stream>>>(C4, bufB, bufE, bufA, bufF, KV, 2 * S);

  // proj (split-K 4), m2 tail
  zero_buf4<<<dim3(ZG), blk, 0, stream>>>((float4*)bufB, S4);
  gemm1x1_split<<<dim3(32, 2, 16), blk, 0, stream>>>(KV, KV + 2 * S, proj_w, bufB, 1024, 512, 256, 256, 2);
  gemm1x1_big<<<dim3(32, 8, 4), blk, 0, stream>>>(bufB, bufB, m2_inv_w, C4, nullptr, m2_inv_bias, 256, 256, 1024, 3);
  dwconv3<<<dim3(4096), blk, 0, stream>>>(C4, m2_dw_w, D4, nullptr, m2_dw_bias, 1023, 3);
  zero_buf4<<<dim3(ZG), blk, 0, stream>>>((float4*)outp, S4);
  gemm1x1_split<<<dim3(32, 2, 16), blk, 0, stream>>>(D4, D4, m2_pw_w, outp, 1024, 1024, 256, 256, 2);
  epi_pass<<<dim3(ZG), blk, 0, stream>>>(outp, m2_pw_g, m2_pw_b, 255, 1);
}

// Round 6
// 1081.633 us; speedup vs baseline: 1.6169x; 1.6169x over previous
//
#include <hip/hip_runtime.h>

#define HW 4096

__device__ __forceinline__ float hswish(float x) {
  float r = fminf(fmaxf(x + 3.0f, 0.0f), 6.0f);
  return x * r * (1.0f / 6.0f);
}

__device__ __forceinline__ void atomic_add_f32(float* p, float v) {
  __hip_atomic_fetch_add(p, v, __ATOMIC_RELAXED, __HIP_MEMORY_SCOPE_AGENT);
}

__global__ __launch_bounds__(256) void zero_buf4(float4* __restrict__ p, int n4) {
  int i = blockIdx.x * 256 + threadIdx.x;
  if (i < n4) p[i] = make_float4(0.f, 0.f, 0.f, 0.f);
}

// 1x1 conv GEMM. 64p x 128co tile, BK=16, 256 threads, 4p x 8co per thread.
// Register-prefetch pipeline over K. Grid dim3(64, CO/128, B).
// out[b,co,p] = sum_k W[co,k]*in(b,k,p); k<k0 from in0 else in1 (fused concat).
// epi: 0 none, 1 g*x+b, 2 hswish(g*x+b), 3 hswish(x+bias)
__global__ __launch_bounds__(256) void gemm1x1_med(
    const float* __restrict__ in0, const float* __restrict__ in1,
    const float* __restrict__ W, float* __restrict__ out,
    const float* __restrict__ scale, const float* __restrict__ bias,
    int K, int k0, int CO, int epi)
{
  __shared__ float At[16][64];    // [k][p]   4 KB
  __shared__ float Wt[16][128];   // [k][co]  8 KB
  const int p0  = blockIdx.x * 64;
  const int co0 = blockIdx.y * 128;
  const int b   = blockIdx.z;
  const int tid = threadIdx.x;
  const int tx = tid & 15, ty = tid >> 4;       // tx: p-quad, ty: co-oct
  const int k1 = K - k0;
  // A staging map: k = tid>>4, p4 = (tid&15)*4
  const int ak = tid >> 4, ap = (tid & 15) << 2;
  // W staging map: two float4s: co_a = tid>>2, co_b = 64+co_a, wk = (tid&3)*4
  const int wco = tid >> 2, wk = (tid & 3) << 2;

  float4 abuf, wbuf0, wbuf1;
  {
    const float* src = (ak < k0)
        ? in0 + ((size_t)b * k0 + ak) * HW
        : in1 + ((size_t)b * k1 + (ak - k0)) * HW;
    abuf = *(const float4*)(src + p0 + ap);
    wbuf0 = *(const float4*)(W + (size_t)(co0 + wco) * K + wk);
    wbuf1 = *(const float4*)(W + (size_t)(co0 + 64 + wco) * K + wk);
  }

  float acc[8][4] = {};
  for (int kt = 0; kt < K; kt += 16) {
    // write staged regs to LDS
    *(float4*)&At[ak][ap] = abuf;
    Wt[wk + 0][wco] = wbuf0.x; Wt[wk + 1][wco] = wbuf0.y;
    Wt[wk + 2][wco] = wbuf0.z; Wt[wk + 3][wco] = wbuf0.w;
    Wt[wk + 0][64 + wco] = wbuf1.x; Wt[wk + 1][64 + wco] = wbuf1.y;
    Wt[wk + 2][64 + wco] = wbuf1.z; Wt[wk + 3][64 + wco] = wbuf1.w;
    __syncthreads();
    // prefetch next K-tile into regs (overlaps with compute below)
    if (kt + 16 < K) {
      int kg = kt + 16 + ak;
      const float* src = (kg < k0)
          ? in0 + ((size_t)b * k0 + kg) * HW
          : in1 + ((size_t)b * k1 + (kg - k0)) * HW;
      abuf = *(const float4*)(src + p0 + ap);
      wbuf0 = *(const float4*)(W + (size_t)(co0 + wco) * K + kt + 16 + wk);
      wbuf1 = *(const float4*)(W + (size_t)(co0 + 64 + wco) * K + kt + 16 + wk);
    }
    #pragma unroll
    for (int k = 0; k < 16; ++k) {
      float4 a  = *(const float4*)&At[k][tx << 2];
      float4 w0 = *(const float4*)&Wt[k][ty << 3];
      float4 w1 = *(const float4*)&Wt[k][(ty << 3) + 4];
      float av[4] = {a.x, a.y, a.z, a.w};
      float wv[8] = {w0.x, w0.y, w0.z, w0.w, w1.x, w1.y, w1.z, w1.w};
      #pragma unroll
      for (int i = 0; i < 8; ++i)
        #pragma unroll
        for (int j = 0; j < 4; ++j)
          acc[i][j] = fmaf(wv[i], av[j], acc[i][j]);
    }
    __syncthreads();
  }
  #pragma unroll
  for (int i = 0; i < 8; ++i) {
    int co = co0 + (ty << 3) + i;
    float g = 1.0f, bb = 0.0f;
    if (epi == 1 || epi == 2) { g = scale[co]; bb = bias[co]; }
    else if (epi == 3) { bb = bias[co]; }
    float vv[4];
    #pragma unroll
    for (int j = 0; j < 4; ++j) {
      float v = acc[i][j];
      if (epi == 1)      v = v * g + bb;
      else if (epi == 2) v = hswish(v * g + bb);
      else if (epi == 3) v = hswish(v + bb);
      vv[j] = v;
    }
    *(float4*)(out + ((size_t)b * CO + co) * HW + p0 + (tx << 2)) =
        make_float4(vv[0], vv[1], vv[2], vv[3]);
  }
}

// LDS-tiled depthwise 3x3, pad 1, branch-free inner loop. One block per (b,c).
// epi: 2 hswish(scale*x+bias), 3 hswish(x+bias)
__global__ __launch_bounds__(256) void dwconv3(
    const float* __restrict__ in, const float* __restrict__ w,
    float* __restrict__ out, const float* __restrict__ scale,
    const float* __restrict__ bias, int Cmask, int epi)
{
  __shared__ float tl[66 * 66];
  const int bc = blockIdx.x;
  const int c  = bc & Cmask;
  const float* src = in + (size_t)bc * HW;
  const int t = threadIdx.x;
  for (int i = t; i < 66 * 66; i += 256) {
    int r = i / 66, cc = i - r * 66;
    int gy = r - 1, gx = cc - 1;
    float v = 0.0f;
    if (gy >= 0 && gy < 64 && gx >= 0 && gx < 64) v = src[(gy << 6) + gx];
    tl[i] = v;
  }
  const float* wp = w + c * 9;
  float w00 = wp[0], w01 = wp[1], w02 = wp[2];
  float w10 = wp[3], w11 = wp[4], w12 = wp[5];
  float w20 = wp[6], w21 = wp[7], w22 = wp[8];
  float g = (epi == 2) ? scale[c] : 1.0f;
  float bb = bias[c];
  __syncthreads();
  float* op = out + (size_t)bc * HW;
  #pragma unroll 4
  for (int j = 0; j < 16; ++j) {
    int p = j * 256 + t;
    int y = p >> 6, x = p & 63;
    const float* bp = &tl[y * 66 + x];
    float s;
    s = w00 * bp[0]        + w01 * bp[1]        + w02 * bp[2];
    s = fmaf(w10, bp[66],    fmaf(w11, bp[67],    fmaf(w12, bp[68],  s)));
    s = fmaf(w20, bp[132],   fmaf(w21, bp[133],   fmaf(w22, bp[134], s)));
    float v = (epi == 2) ? hswish(s * g + bb) : hswish(s + bb);
    op[p] = v;
  }
}

// Fused dw5x5(pad2) + grouped 1x1 (32->32 per group).
__global__ __launch_bounds__(256) void agg_fused(
    const float* __restrict__ in, const float* __restrict__ dw,
    const float* __restrict__ pw, float* __restrict__ out, int C)
{
  __shared__ float in_t[16 * 12 * 68];
  __shared__ float dww[32 * 25];
  __shared__ float pww[32 * 32];
  const int g = blockIdx.x, b = blockIdx.y, tile = blockIdx.z;
  const int t = threadIdx.x;
  const int y0 = tile * 8;
  const float* src = in + ((size_t)b * C + g * 32) * HW;

  for (int i = t; i < 800; i += 256)  dww[i] = dw[(size_t)g * 800 + i];
  for (int i = t; i < 1024; i += 256) pww[i] = pw[(size_t)g * 1024 + i];

  const int x = t & 63, yl = t >> 6;
  float acca[32] = {}, accb[32] = {};

  for (int ph = 0; ph < 2; ++ph) {
    __syncthreads();
    #pragma unroll
    for (int i = 0; i < 12; ++i) {
      int id = i * 256 + t;
      int q = id & 15;
      int rid = id >> 4;
      int ch = rid / 12, r = rid - ch * 12;
      int gy = y0 - 2 + r;
      float4 v = make_float4(0.f, 0.f, 0.f, 0.f);
      if (gy >= 0 && gy < 64)
        v = *(const float4*)(src + (size_t)(ph * 16 + ch) * HW + (gy << 6) + (q << 2));
      *(float4*)&in_t[(ch * 12 + r) * 68 + 2 + (q << 2)] = v;
    }
    #pragma unroll
    for (int i = 0; i < 3; ++i) {
      int id = i * 256 + t;
      int side = id & 3;
      int rid = id >> 2;
      int col = (side < 2) ? side : 64 + side;
      in_t[rid * 68 + col] = 0.0f;
    }
    __syncthreads();
    for (int cl = 0; cl < 16; ++cl) {
      int ci = ph * 16 + cl;
      const float* bp = &in_t[(cl * 12) * 68 + 2 + x];
      const float* wv = &dww[ci * 25];
      float da = 0.f, db = 0.f;
      #pragma unroll
      for (int k = 0; k < 25; ++k) {
        int dy = k / 5, dx = (k % 5) - 2;
        float w = wv[k];
        da = fmaf(w, bp[(yl + dy) * 68 + dx], da);
        db = fmaf(w, bp[(yl + 4 + dy) * 68 + dx], db);
      }
      #pragma unroll
      for (int m = 0; m < 32; ++m) {
        float w = pww[m * 32 + ci];
        acca[m] = fmaf(w, da, acca[m]);
        accb[m] = fmaf(w, db, accb[m]);
      }
    }
  }
  float* dst = out + ((size_t)b * C + g * 32) * HW + y0 * 64;
  #pragma unroll
  for (int m = 0; m < 32; ++m) {
    dst[(size_t)m * HW + (yl << 6) + x]        = acca[m];
    dst[(size_t)m * HW + ((yl + 4) << 6) + x]  = accb[m];
  }
}

// Attention phase A: partial ctx = K^T [V|1] over a 128-n slice, atomicAdd to ctxbuf.
__global__ __launch_bounds__(256) void att_ctx(
    const float* __restrict__ kv, const float* __restrict__ kvs,
    float* __restrict__ ctxbuf)
{
  __shared__ float kvt[64][129];
  const int head  = blockIdx.x;
  const int b     = blockIdx.y;
  const int slice = blockIdx.z & 31;
  const int z     = blockIdx.z >> 5;
  const int tid   = threadIdx.x;

  const float* kvsrc = (head < 8)
      ? kv  + ((size_t)b * 1024 + z * 512 + head * 64) * HW
      : kvs + ((size_t)b * 1024 + z * 512 + (head - 8) * 64) * HW;
  const int n0 = slice * 128;

  #pragma unroll
  for (int l = 0; l < 8; ++l) {
    int fid = tid + l * 256;
    int ch = fid >> 5;
    int nc = (fid & 31) << 2;
    float4 v = *(const float4*)(kvsrc + (size_t)ch * HW + n0 + nc);
    if (ch < 32) {
      v.x = fmaxf(v.x, 0.0f); v.y = fmaxf(v.y, 0.0f);
      v.z = fmaxf(v.z, 0.0f); v.w = fmaxf(v.w, 0.0f);
    }
    kvt[ch][nc] = v.x; kvt[ch][nc + 1] = v.y;
    kvt[ch][nc + 2] = v.z; kvt[ch][nc + 3] = v.w;
  }
  __syncthreads();

  const int td = tid & 15, te = tid >> 4;
  const int d0 = td * 2, e0 = te * 2;
  float a00 = 0, a01 = 0, a10 = 0, a11 = 0, c0 = 0, c1 = 0;
  #pragma unroll 8
  for (int nn = 0; nn < 128; ++nn) {
    float k0 = kvt[d0][nn], k1 = kvt[d0 + 1][nn];
    float v0 = kvt[32 + e0][nn], v1 = kvt[32 + e0 + 1][nn];
    a00 = fmaf(k0, v0, a00); a01 = fmaf(k0, v1, a01);
    a10 = fmaf(k1, v0, a10); a11 = fmaf(k1, v1, a11);
    c0 += k0; c1 += k1;
  }
  float* cp = ctxbuf + (size_t)(((z * 4 + b) * 16) + head) * 1056;
  atomic_add_f32(&cp[(d0 + 0) * 33 + e0 + 0], a00);
  atomic_add_f32(&cp[(d0 + 0) * 33 + e0 + 1], a01);
  atomic_add_f32(&cp[(d0 + 1) * 33 + e0 + 0], a10);
  atomic_add_f32(&cp[(d0 + 1) * 33 + e0 + 1], a11);
  if (te == 0) {
    atomic_add_f32(&cp[(d0 + 0) * 33 + 32], c0);
    atomic_add_f32(&cp[(d0 + 1) * 33 + 32], c1);
  }
}

// Attention phase B.
__global__ __launch_bounds__(256) void att_apply(
    const float* __restrict__ ctxbuf,
    const float* __restrict__ q0, const float* __restrict__ q0s,
    const float* __restrict__ q1, const float* __restrict__ q1s,
    float* __restrict__ outbase, size_t outstride)
{
  __shared__ float ctx[1056];
  const int head = blockIdx.x;
  const int b    = blockIdx.y;
  const int tile = blockIdx.z & 15;
  const int z    = blockIdx.z >> 4;
  const int tid  = threadIdx.x;

  const float* cp = ctxbuf + (size_t)(((z * 4 + b) * 16) + head) * 1056;
  for (int i = tid; i < 1056; i += 256) ctx[i] = cp[i];
  __syncthreads();

  const float* qb = (z == 0) ? (head < 8 ? q0 : q0s) : (head < 8 ? q1 : q1s);
  const float* qsrc = qb + ((size_t)b * 256 + (head & 7) * 32) * HW;
  float* outp = outbase + (size_t)z * outstride + ((size_t)b * 512 + head * 32) * HW;

  const int n = tile * 256 + tid;
  float qv[32];
  #pragma unroll
  for (int d = 0; d < 32; ++d)
    qv[d] = fmaxf(qsrc[(size_t)d * HW + n], 0.0f);
  float den = 1e-15f;
  #pragma unroll
  for (int d = 0; d < 32; ++d)
    den = fmaf(qv[d], ctx[d * 33 + 32], den);
  float rden = 1.0f / den;
  for (int e = 0; e < 32; ++e) {
    float s = 0.0f;
    #pragma unroll
    for (int d = 0; d < 32; ++d)
      s = fmaf(qv[d], ctx[d * 33 + e], s);
    outp[(size_t)e * HW + n] = s * rden;
  }
}

extern "C" void kernel_launch(void* const* d_in, const int* in_sizes, int n_in,
                              void* d_out, int out_size, void* d_ws, size_t ws_size,
                              hipStream_t stream) {
  (void)in_sizes; (void)n_in; (void)out_size; (void)ws_size;
  const float* rgb         = (const float*)d_in[0];
  const float* t           = (const float*)d_in[1];
  const float* m1_inv_w    = (const float*)d_in[2];
  const float* m1_inv_g    = (const float*)d_in[3];
  const float* m1_inv_b    = (const float*)d_in[4];
  const float* m1_dw_w     = (const float*)d_in[5];
  const float* m1_dw_g     = (const float*)d_in[6];
  const float* m1_dw_b     = (const float*)d_in[7];
  const float* m1_pw_w     = (const float*)d_in[8];
  const float* m1_pw_g     = (const float*)d_in[9];
  const float* m1_pw_b     = (const float*)d_in[10];
  const float* kv_w        = (const float*)d_in[11];
  const float* qrgb_w      = (const float*)d_in[12];
  const float* qt_w        = (const float*)d_in[13];
  const float* agg_kv_dw   = (const float*)d_in[14];
  const float* agg_kv_pw   = (const float*)d_in[15];
  const float* agg_t_dw    = (const float*)d_in[16];
  const float* agg_t_pw    = (const float*)d_in[17];
  const float* agg_rgb_dw  = (const float*)d_in[18];
  const float* agg_rgb_pw  = (const float*)d_in[19];
  const float* proj_w      = (const float*)d_in[20];
  const float* m2_inv_w    = (const float*)d_in[21];
  const float* m2_inv_bias = (const float*)d_in[22];
  const float* m2_dw_w     = (const float*)d_in[23];
  const float* m2_dw_bias  = (const float*)d_in[24];
  const float* m2_pw_w     = (const float*)d_in[25];
  const float* m2_pw_g     = (const float*)d_in[26];
  const float* m2_pw_b     = (const float*)d_in[27];
  float* outp = (float*)d_out;

  const size_t S = (size_t)4 * 256 * HW;   // one (B,256,64,64) fp32 tensor
  float* ws   = (float*)d_ws;
  float* bufA = ws;            // S
  float* bufB = ws + S;        // S
  float* bufE = ws + 2 * S;    // S (qt_s)
  float* bufF = ws + 3 * S;    // S (qrgb_s)
  float* KV   = ws + 4 * S;    // 4S (kv; later out1|out2)
  float* C4   = ws + 8 * S;    // 4S (ctxbuf; later m2_inv out)
  float* D4   = ws + 12 * S;   // 4S (kv_s; later m2_dw out)

  dim3 blk(256);

  // m1 stem
  gemm1x1_med<<<dim3(64, 2, 4), blk, 0, stream>>>(rgb, t, m1_inv_w, bufA, m1_inv_g, m1_inv_b, 512, 256, 256, 2);
  dwconv3<<<dim3(1024), blk, 0, stream>>>(bufA, m1_dw_w, bufB, m1_dw_g, m1_dw_b, 255, 2);
  gemm1x1_med<<<dim3(64, 2, 4), blk, 0, stream>>>(bufB, bufB, m1_pw_w, bufA, m1_pw_g, m1_pw_b, 256, 256, 256, 1); // rgbt -> A

  // projections
  gemm1x1_med<<<dim3(64, 8, 4), blk, 0, stream>>>(bufA, bufA, kv_w, KV, nullptr, nullptr, 256, 256, 1024, 0);     // kv
  gemm1x1_med<<<dim3(64, 2, 4), blk, 0, stream>>>(t, t, qt_w, bufB, nullptr, nullptr, 256, 256, 256, 0);          // q_t -> B
  gemm1x1_med<<<dim3(64, 2, 4), blk, 0, stream>>>(rgb, rgb, qrgb_w, bufA, nullptr, nullptr, 256, 256, 256, 0);    // q_rgb -> A

  // fused multi-scale aggregation (dw5x5 + grouped 1x1)
  agg_fused<<<dim3(32, 4, 8), blk, 0, stream>>>(KV,  agg_kv_dw,  agg_kv_pw,  D4,  1024);  // kv_s -> D4
  agg_fused<<<dim3(8, 4, 8),  blk, 0, stream>>>(bufB, agg_t_dw,  agg_t_pw,  bufE, 256);   // qt_s -> E
  agg_fused<<<dim3(8, 4, 8),  blk, 0, stream>>>(bufA, agg_rgb_dw, agg_rgb_pw, bufF, 256); // qrgb_s -> F

  // attention
  zero_buf4<<<dim3(132), blk, 0, stream>>>((float4*)C4, 128 * 264);
  att_ctx<<<dim3(16, 4, 64), blk, 0, stream>>>(KV, D4, C4);
  att_apply<<<dim3(16, 4, 32), blk, 0, stream>>>(C4, bufB, bufE, bufA, bufF, KV, 2 * S);

  // projection + m2 tail
  gemm1x1_med<<<dim3(64, 2, 4), blk, 0, stream>>>(KV, KV + 2 * S, proj_w, bufB, nullptr, nullptr, 1024, 512, 256, 0);
  gemm1x1_med<<<dim3(64, 8, 4), blk, 0, stream>>>(bufB, bufB, m2_inv_w, C4, nullptr, m2_inv_bias, 256, 256, 1024, 3);
  dwconv3<<<dim3(4096), blk, 0, stream>>>(C4, m2_dw_w, D4, nullptr, m2_dw_bias, 1023, 3);
  gemm1x1_med<<<dim3(64, 2, 4), blk, 0, stream>>>(D4, D4, m2_pw_w, outp, m2_pw_g, m2_pw_b, 1024, 1024, 256, 1);
}